// Round 11
// baseline (58.191 us; speedup 1.0000x reference)
//
#include <hip/hip_runtime.h>

#define B_N 8
#define C_N 8
#define F_N 257
#define T_N 2000
#define TQ_N (T_N / 4)      // 500 float4 per (b,f) row
#define EPSF 1e-6f
#define PER_B (C_N * F_N * TQ_N)   // 1,028,000 float4 per batch

#define FCH 32              // F chunks
#define FPC 9               // ceil(257/32) rows per chunk

typedef float f32x4 __attribute__((ext_vector_type(4)));

// ---- Kernel A: partial |X[b,rc,f,t]| sums over an F-chunk. 256 blocks. ----
__global__ __launch_bounds__(512) void partial_mean_kernel(
    const float* __restrict__ X, const int* __restrict__ ref_ch,
    f32x4* __restrict__ part4 /* [B][FCH][TQ_N] */)
{
    const int b = blockIdx.x, c = blockIdx.y, tid = threadIdx.x;
    if (tid >= TQ_N) return;

    const int rc = ref_ch[0];
    const f32x4* Xb4 =
        (const f32x4*)(X + ((size_t)(b * C_N + rc)) * (size_t)F_N * T_N);

    const int f0 = c * FPC;
    const int f1 = (f0 + FPC < F_N) ? (f0 + FPC) : F_N;

    f32x4 acc = {0.f, 0.f, 0.f, 0.f};
    for (int f = f0; f < f1; ++f) {
        f32x4 v = Xb4[f * TQ_N + tid];
        acc.x += fabsf(v.x); acc.y += fabsf(v.y);
        acc.z += fabsf(v.z); acc.w += fabsf(v.w);
    }
    part4[(b * FCH + c) * TQ_N + tid] = acc;
}

// ---- Kernel B: reduce partials -> mean, parallel affine scan ->
//      inv[b][t] = 1/(mu_t + eps). One block per batch. ----
__global__ __launch_bounds__(512) void scan_kernel(
    const f32x4* __restrict__ part4,
    f32x4* __restrict__ inv4 /* [B][TQ_N] */)
{
    __shared__ float s_mean[T_N];
    __shared__ float s_wA[8];
    __shared__ float s_wB[8];
    const float ALPHA = (float)(191.0 / 193.0);
    const int b = blockIdx.x, tid = threadIdx.x;

    if (tid < TQ_N) {
        f32x4 s = {0.f, 0.f, 0.f, 0.f};
        #pragma unroll
        for (int c = 0; c < FCH; ++c)
            s += part4[(b * FCH + c) * TQ_N + tid];
        const int t = tid * 4;
        const float inv_f = 1.f / (float)F_N;
        s_mean[t + 0] = s.x * inv_f; s_mean[t + 1] = s.y * inv_f;
        s_mean[t + 2] = s.z * inv_f; s_mean[t + 3] = s.w * inv_f;
    }
    __syncthreads();

    // Affine scan: transform (A,B): mu -> A*mu + B. Local composite of 4 t's.
    float A = 1.f, Bv = 0.f;
    const int tbase = tid * 4;
    #pragma unroll
    for (int k = 0; k < 4; ++k) {
        const int t = tbase + k;
        if (t < T_N) {
            const float tf = (float)t;
            const float a = fminf((tf - 1.f) / (tf + 1.f), ALPHA);
            Bv = a * Bv + (1.f - a) * s_mean[t];
            A  = a * A;
        }
    }
    const int lane = tid & 63;
    #pragma unroll
    for (int d = 1; d < 64; d <<= 1) {
        const float pA = __shfl_up(A, d);
        const float pB = __shfl_up(Bv, d);
        if (lane >= d) { Bv = A * pB + Bv; A = A * pA; }
    }
    const int wid = tid >> 6;
    if (lane == 63) { s_wA[wid] = A; s_wB[wid] = Bv; }
    __syncthreads();
    if (tid == 0) {
        float cA = 1.f, cB = 0.f;
        #pragma unroll
        for (int w = 0; w < 8; ++w) {
            const float nA = s_wA[w] * cA;
            const float nB = s_wA[w] * cB + s_wB[w];
            s_wA[w] = cA; s_wB[w] = cB;
            cA = nA; cB = nB;
        }
    }
    __syncthreads();
    float eA = __shfl_up(A, 1);
    float eB = __shfl_up(Bv, 1);
    if (lane == 0) { eA = 1.f; eB = 0.f; }
    float mu = eA * s_wB[wid] + eB;   // applied to mu0 = 0

    if (tid < TQ_N) {
        f32x4 r;
        #pragma unroll
        for (int k = 0; k < 4; ++k) {
            const int t = tbase + k;
            const float tf = (float)t;
            const float a = fminf((tf - 1.f) / (tf + 1.f), ALPHA);
            mu = a * mu + (1.f - a) * s_mean[t];
            r[k] = 1.f / (mu + EPSF);
        }
        inv4[b * TQ_N + tid] = r;
    }
}

// ---- Kernel C: streaming out = X * inv[b,t], 2 float4 per thread (ILP),
//      cached X load (L3-friendly), NT store for out. ----
__global__ __launch_bounds__(256) void norm_kernel(
    const f32x4* __restrict__ X4,
    const f32x4* __restrict__ inv4,
    f32x4* __restrict__ out4)
{
    const int b = blockIdx.y;
    const f32x4* Xb  = X4   + (size_t)b * PER_B;
    f32x4*       Ob  = out4 + (size_t)b * PER_B;
    const f32x4* ivb = inv4 + b * TQ_N;

    const int i = blockIdx.x * 512 + threadIdx.x * 2;   // even
    if (i + 1 < PER_B) {
        const int tq0 = i % TQ_N;                       // even => tq0 <= 498
        const f32x4 x0 = Xb[i];
        const f32x4 x1 = Xb[i + 1];
        const f32x4 r0 = x0 * ivb[tq0];
        const f32x4 r1 = x1 * ivb[tq0 + 1];
        __builtin_nontemporal_store(r0, Ob + i);
        __builtin_nontemporal_store(r1, Ob + i + 1);
    } else if (i < PER_B) {
        const int tq0 = i % TQ_N;
        __builtin_nontemporal_store(Xb[i] * ivb[tq0], Ob + i);
    }
}

extern "C" void kernel_launch(void* const* d_in, const int* in_sizes, int n_in,
                              void* d_out, int out_size, void* d_ws, size_t ws_size,
                              hipStream_t stream) {
    const float* X  = (const float*)d_in[0];
    const int*   rc = (const int*)d_in[1];

    f32x4* inv  = (f32x4*)d_ws;                 // 8*500*16      = 64 KB
    f32x4* part = inv + B_N * TQ_N;             // 8*32*500*16   = 2.048 MB

    dim3 gA(B_N, FCH);
    partial_mean_kernel<<<gA, 512, 0, stream>>>(X, rc, part);

    scan_kernel<<<B_N, 512, 0, stream>>>(part, inv);

    dim3 gC((PER_B + 511) / 512, B_N);
    norm_kernel<<<gC, 256, 0, stream>>>((const f32x4*)X, inv, (f32x4*)d_out);
}

// Round 12
// 52.908 us; speedup vs baseline: 1.0998x; 1.0998x over previous
//
#include <hip/hip_runtime.h>

#define B_N 8
#define C_N 8
#define F_N 257
#define T_N 2000
#define TQ_N (T_N / 4)      // 500 float4 per (b,f) row
#define EPSF 1e-6f
#define PER_B (C_N * F_N * TQ_N)   // 1,028,000 float4 per batch

#define FCH 32              // F chunks
#define FPC 9               // ceil(257/32) rows per chunk

typedef float f32x4 __attribute__((ext_vector_type(4)));

// ---- Kernel A: partial |X[b,rc,f,t]| sums over an F-chunk. 256 blocks. ----
__global__ __launch_bounds__(512) void partial_mean_kernel(
    const float* __restrict__ X, const int* __restrict__ ref_ch,
    f32x4* __restrict__ part4 /* [B][FCH][TQ_N] */)
{
    const int b = blockIdx.x, c = blockIdx.y, tid = threadIdx.x;
    if (tid >= TQ_N) return;

    const int rc = ref_ch[0];
    const f32x4* Xb4 =
        (const f32x4*)(X + ((size_t)(b * C_N + rc)) * (size_t)F_N * T_N);

    const int f0 = c * FPC;
    const int f1 = (f0 + FPC < F_N) ? (f0 + FPC) : F_N;

    f32x4 acc = {0.f, 0.f, 0.f, 0.f};
    for (int f = f0; f < f1; ++f) {
        f32x4 v = Xb4[f * TQ_N + tid];
        acc.x += fabsf(v.x); acc.y += fabsf(v.y);
        acc.z += fabsf(v.z); acc.w += fabsf(v.w);
    }
    part4[(b * FCH + c) * TQ_N + tid] = acc;
}

// ---- Kernel B: reduce partials -> mean, parallel affine scan ->
//      inv[b][t] = 1/(mu_t + eps). One block per batch. ----
__global__ __launch_bounds__(512) void scan_kernel(
    const f32x4* __restrict__ part4,
    f32x4* __restrict__ inv4 /* [B][TQ_N] */)
{
    __shared__ float s_mean[T_N];
    __shared__ float s_wA[8];
    __shared__ float s_wB[8];
    const float ALPHA = (float)(191.0 / 193.0);
    const int b = blockIdx.x, tid = threadIdx.x;

    if (tid < TQ_N) {
        f32x4 s = {0.f, 0.f, 0.f, 0.f};
        #pragma unroll
        for (int c = 0; c < FCH; ++c)
            s += part4[(b * FCH + c) * TQ_N + tid];
        const int t = tid * 4;
        const float inv_f = 1.f / (float)F_N;
        s_mean[t + 0] = s.x * inv_f; s_mean[t + 1] = s.y * inv_f;
        s_mean[t + 2] = s.z * inv_f; s_mean[t + 3] = s.w * inv_f;
    }
    __syncthreads();

    // Affine scan: transform (A,B): mu -> A*mu + B. Local composite of 4 t's.
    float A = 1.f, Bv = 0.f;
    const int tbase = tid * 4;
    #pragma unroll
    for (int k = 0; k < 4; ++k) {
        const int t = tbase + k;
        if (t < T_N) {
            const float tf = (float)t;
            const float a = fminf((tf - 1.f) / (tf + 1.f), ALPHA);
            Bv = a * Bv + (1.f - a) * s_mean[t];
            A  = a * A;
        }
    }
    const int lane = tid & 63;
    #pragma unroll
    for (int d = 1; d < 64; d <<= 1) {
        const float pA = __shfl_up(A, d);
        const float pB = __shfl_up(Bv, d);
        if (lane >= d) { Bv = A * pB + Bv; A = A * pA; }
    }
    const int wid = tid >> 6;
    if (lane == 63) { s_wA[wid] = A; s_wB[wid] = Bv; }
    __syncthreads();
    if (tid == 0) {
        float cA = 1.f, cB = 0.f;
        #pragma unroll
        for (int w = 0; w < 8; ++w) {
            const float nA = s_wA[w] * cA;
            const float nB = s_wA[w] * cB + s_wB[w];
            s_wA[w] = cA; s_wB[w] = cB;
            cA = nA; cB = nB;
        }
    }
    __syncthreads();
    float eA = __shfl_up(A, 1);
    float eB = __shfl_up(Bv, 1);
    if (lane == 0) { eA = 1.f; eB = 0.f; }
    float mu = eA * s_wB[wid] + eB;   // applied to mu0 = 0

    if (tid < TQ_N) {
        f32x4 r;
        #pragma unroll
        for (int k = 0; k < 4; ++k) {
            const int t = tbase + k;
            const float tf = (float)t;
            const float a = fminf((tf - 1.f) / (tf + 1.f), ALPHA);
            mu = a * mu + (1.f - a) * s_mean[t];
            r[k] = 1.f / (mu + EPSF);
        }
        inv4[b * TQ_N + tid] = r;
    }
}

// ---- Kernel C: streaming out = X * inv[b,t]. 2 float4/thread ILP with
//      block-span stride (both instructions stay lane-contiguous).
//      Cached X load (L3-friendly), NT store for out. ----
__global__ __launch_bounds__(256) void norm_kernel(
    const f32x4* __restrict__ X4,
    const f32x4* __restrict__ inv4,
    f32x4* __restrict__ out4)
{
    const int b = blockIdx.y;
    const f32x4* Xb  = X4   + (size_t)b * PER_B;
    f32x4*       Ob  = out4 + (size_t)b * PER_B;
    const f32x4* ivb = inv4 + b * TQ_N;

    const int i0 = blockIdx.x * 512 + threadIdx.x;
    const int i1 = i0 + 256;

    if (i1 < PER_B) {
        const int tq0 = i0 % TQ_N;
        int tq1 = tq0 + 256; if (tq1 >= TQ_N) tq1 -= TQ_N;
        const f32x4 x0 = Xb[i0];
        const f32x4 x1 = Xb[i1];
        __builtin_nontemporal_store(x0 * ivb[tq0], Ob + i0);
        __builtin_nontemporal_store(x1 * ivb[tq1], Ob + i1);
    } else if (i0 < PER_B) {
        const int tq0 = i0 % TQ_N;
        __builtin_nontemporal_store(Xb[i0] * ivb[tq0], Ob + i0);
    }
}

extern "C" void kernel_launch(void* const* d_in, const int* in_sizes, int n_in,
                              void* d_out, int out_size, void* d_ws, size_t ws_size,
                              hipStream_t stream) {
    const float* X  = (const float*)d_in[0];
    const int*   rc = (const int*)d_in[1];

    f32x4* inv  = (f32x4*)d_ws;                 // 8*500*16      = 64 KB
    f32x4* part = inv + B_N * TQ_N;             // 8*32*500*16   = 2.048 MB

    dim3 gA(B_N, FCH);
    partial_mean_kernel<<<gA, 512, 0, stream>>>(X, rc, part);

    scan_kernel<<<B_N, 512, 0, stream>>>(part, inv);

    dim3 gC((PER_B + 511) / 512, B_N);
    norm_kernel<<<gC, 256, 0, stream>>>((const f32x4*)X, inv, (f32x4*)d_out);
}